// Round 2
// baseline (3633.779 us; speedup 1.0000x reference)
//
#include <hip/hip_runtime.h>
#include <stdint.h>

typedef __attribute__((ext_vector_type(8))) __bf16 bf16x8;
typedef __attribute__((ext_vector_type(4))) float  f32x4;

#define SCOPE_AGENT __HIP_MEMORY_SCOPE_AGENT
#define MFMA16(a,b,c) __builtin_amdgcn_mfma_f32_16x16x32_bf16(a,b,c,0,0,0)

__device__ __forceinline__ float sigm(float x){ return 1.0f/(1.0f + __expf(-x)); }
__device__ __forceinline__ float tanh_s(float x){
  float a = fabsf(x);
  float e = __expf(2.0f*a);            // overflow -> inf -> t = 1 (safe)
  float t = 1.0f - 2.0f/(e + 1.0f);
  return x < 0.0f ? -t : t;
}

__device__ __forceinline__ bf16x8 cvt_hi(const float4& a, const float4& b){
  bf16x8 r;
  r[0]=(__bf16)a.x; r[1]=(__bf16)a.y; r[2]=(__bf16)a.z; r[3]=(__bf16)a.w;
  r[4]=(__bf16)b.x; r[5]=(__bf16)b.y; r[6]=(__bf16)b.z; r[7]=(__bf16)b.w;
  return r;
}
__device__ __forceinline__ bf16x8 cvt_lo(const float4& a, const float4& b, bf16x8 hi){
  bf16x8 r;
  r[0]=(__bf16)(a.x-(float)hi[0]); r[1]=(__bf16)(a.y-(float)hi[1]);
  r[2]=(__bf16)(a.z-(float)hi[2]); r[3]=(__bf16)(a.w-(float)hi[3]);
  r[4]=(__bf16)(b.x-(float)hi[4]); r[5]=(__bf16)(b.y-(float)hi[5]);
  r[6]=(__bf16)(b.z-(float)hi[6]); r[7]=(__bf16)(b.w-(float)hi[7]);
  return r;
}

__global__ void fill_sentinel(float* p, int n){
  int i = blockIdx.x*blockDim.x + threadIdx.x;
  if(i < n) p[i] = 12345.0f;
}

// ---------------- fused BiLSTM layer ----------------
// grid = 64: bid = dir*32 + bg*4 + q. 512 threads (8 waves).
// Block owns h-cols [q*64,(q+1)*64) i.e. gate cols {g*256 + q*64 + [0,64)}.
// Whh/Wih quarter-slices register-resident (bf16; Wih split hi+lo).
// Per step: stage x_t (LDS), exchange h(t-1) quarters with 3 peer blocks via
// global memory + monotonic release/acquire flags, MFMA, gate update.
template<bool LAYER0>
__global__ __launch_bounds__(512) void lstm_fused(
    const float*  __restrict__ xf,     // LAYER0: [128][512][256] f32
    const __bf16* __restrict__ hin,    // !LAYER0: [2][8][512][16][256] bf16
    const float* __restrict__ WihF, const float* __restrict__ WihB, // [1024][256]
    const float* __restrict__ WhhF, const float* __restrict__ WhhB, // [1024][256]
    const float* __restrict__ bihF, const float* __restrict__ bhhF,
    const float* __restrict__ bihB, const float* __restrict__ bhhB,
    __bf16* __restrict__ hout,         // [2][8][512][16][256] bf16
    unsigned int* __restrict__ flags)  // 64 slots x 32 u32
{
  const int tid  = threadIdx.x;
  const int wave = tid>>6, lane = tid&63;
  const int bid  = blockIdx.x;
  const int dir  = bid>>5;
  const int bg   = (bid>>2)&7;
  const int q    = bid&3;

  const float* Wih = dir ? WihB : WihF;
  const float* Whh = dir ? WhhB : WhhF;
  const float* bih = dir ? bihB : bihF;
  const float* bhh = dir ? bhhB : bhhF;
  const __bf16* hinD = LAYER0 ? (const __bf16*)0 : (hin + (size_t)dir*(65536ull*256ull));
  __bf16* houtD = hout + (size_t)dir*(65536ull*256ull);
  unsigned int* myFlag = flags + (size_t)bid*32;

  __shared__ __attribute__((aligned(16))) __bf16 xsh[16*256];  // 8 KB (swizzled)
  __shared__ __attribute__((aligned(16))) __bf16 xsl[16*256];  // 8 KB (layer0 lo part)
  __shared__ __attribute__((aligned(16))) __bf16 hs [16*256];  // 8 KB h(t-1) (swizzled)
  __shared__ __attribute__((aligned(16))) float  gb [16*256];  // 16 KB gates [row][g*64+lc]

  // zero h(-1)
  for(int i=tid;i<512;i+=512) *(uint4*)((char*)hs + i*16) = make_uint4(0,0,0,0);

  // ---- register-resident weights (f32 -> bf16; Wih split hi/lo) ----
  bf16x8 Bwh[2][8], Bwih[2][8], Bwil[2][8];
  float  bias[2];
#pragma unroll
  for(int j=0;j<2;++j){
    int nt = wave*2 + j;
    int gate = nt>>2, sub = nt&3;
    int col = gate*256 + q*64 + sub*16 + (lane&15);
    bias[j] = bih[col] + bhh[col];
    const float* wh = Whh + (size_t)col*256 + (lane>>4)*8;
    const float* wi = Wih + (size_t)col*256 + (lane>>4)*8;
#pragma unroll
    for(int kb=0;kb<8;++kb){
      float4 h0 = *(const float4*)(wh + kb*32);
      float4 h1 = *(const float4*)(wh + kb*32 + 4);
      Bwh[j][kb] = cvt_hi(h0, h1);
      float4 i0 = *(const float4*)(wi + kb*32);
      float4 i1 = *(const float4*)(wi + kb*32 + 4);
      bf16x8 hi = cvt_hi(i0, i1);
      Bwih[j][kb] = hi;
      Bwil[j][kb] = cvt_lo(i0, i1, hi);
    }
  }

  const int srow = tid>>5;          // staging row 0..15
  const int sc8  = (tid&31)*8;      // staging col (elements)
  const int b0r  = bg*16;
  const int urow = tid>>5;          // update row
  const int ulc  = (tid&31)*2;      // update local col (0..62, pairs)
  const int m    = lane&15;         // MFMA A row
  const int kq   = (lane>>4)*16;    // MFMA k byte sub-offset

  float c0 = 0.f, c1 = 0.f;
  __syncthreads();                  // hs zeros visible

  for(int t=0; t<512; ++t){
    // ---- A: load + stage x_t ----
    if constexpr(LAYER0){
      int tx = dir ? (511-t) : t;
      const float* src = xf + (((size_t)(b0r+srow))*512 + tx)*256 + sc8;
      float4 xa = *(const float4*)src;
      float4 xb = *(const float4*)(src+4);
      bf16x8 hi = cvt_hi(xa, xb);
      bf16x8 lo = cvt_lo(xa, xb, hi);
      int off = srow*512 + ((sc8*2) ^ ((srow&7)<<4));
      *(bf16x8*)((char*)xsh + off) = hi;
      *(bf16x8*)((char*)xsl + off) = lo;
    } else {
      bf16x8 xv = *(const bf16x8*)(hinD + (((size_t)bg*512 + t)*16 + srow)*256 + sc8);
      *(bf16x8*)((char*)xsh + srow*512 + ((sc8*2) ^ ((srow&7)<<4))) = xv;
    }
    // ---- wait for 3 peers to have published h(t-1) ----
    if(t>0 && tid<3){
      int p = tid + (tid>=q ? 1 : 0);
      unsigned int* pf = flags + (size_t)(dir*32 + bg*4 + p)*32;
      while(__hip_atomic_load(pf, __ATOMIC_ACQUIRE, SCOPE_AGENT) < (unsigned)t)
        __builtin_amdgcn_s_sleep(1);
    }
    __syncthreads();   // xs staged; peer data globally visible

    // ---- B: issue peer h loads (latency hidden under x-MFMA) ----
    bf16x8 pv; int pOff = 0;
    if(t>0 && tid<384){
      int pi  = tid>>7;
      int p   = pi + (pi>=q ? 1 : 0);
      int row = (tid>>3)&15;
      int l8  = tid&7;
      int coll = p*64 + l8*8;
      pv = *(const bf16x8*)(houtD + (((size_t)bg*512 + (t-1))*16 + row)*256 + coll);
      pOff = row*512 + ((coll*2) ^ ((row&7)<<4));
    }
    // ---- Cx: input-part MFMA (independent of peers) ----
    f32x4 ax0 = {bias[0],bias[0],bias[0],bias[0]};
    f32x4 ax1 = {bias[1],bias[1],bias[1],bias[1]};
#pragma unroll
    for(int kb=0;kb<8;++kb){
      int off = m*512 + ((kb*64 + kq) ^ ((m&7)<<4));
      bf16x8 ah = *(const bf16x8*)((const char*)xsh + off);
      ax0 = MFMA16(ah, Bwih[0][kb], ax0);
      ax1 = MFMA16(ah, Bwih[1][kb], ax1);
      ax0 = MFMA16(ah, Bwil[0][kb], ax0);
      ax1 = MFMA16(ah, Bwil[1][kb], ax1);
      if constexpr(LAYER0){
        bf16x8 al = *(const bf16x8*)((const char*)xsl + off);
        ax0 = MFMA16(al, Bwih[0][kb], ax0);
        ax1 = MFMA16(al, Bwih[1][kb], ax1);
      }
    }
    // ---- write peer h into LDS ----
    if(t>0 && tid<384)
      *(bf16x8*)((char*)hs + pOff) = pv;
    __syncthreads();   // full h(t-1) staged

    // ---- Ch: recurrent-part MFMA ----
    f32x4 ah0 = {0.f,0.f,0.f,0.f};
    f32x4 ah1 = {0.f,0.f,0.f,0.f};
#pragma unroll
    for(int kb=0;kb<8;++kb){
      int off = m*512 + ((kb*64 + kq) ^ ((m&7)<<4));
      bf16x8 hv = *(const bf16x8*)((const char*)hs + off);
      ah0 = MFMA16(hv, Bwh[0][kb], ah0);
      ah1 = MFMA16(hv, Bwh[1][kb], ah1);
    }
    // ---- D: scatter gates ----
#pragma unroll
    for(int j=0;j<2;++j){
      int nt = wave*2 + j;
      int gate = nt>>2, sub = nt&3;
      int lc = gate*64 + sub*16 + m;
#pragma unroll
      for(int i=0;i<4;++i){
        float v = (j ? ax1[i]+ah1[i] : ax0[i]+ah0[i]);
        gb[((lane>>4)*4+i)*256 + lc] = v;
      }
    }
    __syncthreads();
    // ---- E: gate nonlinearities + state update (2 h-cols/thread) ----
    float2 ig = *(const float2*)(gb + urow*256 +   0 + ulc);
    float2 fg = *(const float2*)(gb + urow*256 +  64 + ulc);
    float2 gg = *(const float2*)(gb + urow*256 + 128 + ulc);
    float2 og = *(const float2*)(gb + urow*256 + 192 + ulc);
    c0 = sigm(fg.x)*c0 + sigm(ig.x)*tanh_s(gg.x);
    c1 = sigm(fg.y)*c1 + sigm(ig.y)*tanh_s(gg.y);
    float h0v = sigm(og.x)*tanh_s(c0);
    float h1v = sigm(og.y)*tanh_s(c1);
    union{ __bf16 b[2]; unsigned int u; } hq;
    hq.b[0] = (__bf16)h0v; hq.b[1] = (__bf16)h1v;
    int gc = q*64 + ulc;
    *(unsigned int*)((char*)hs + urow*512 + ((gc*2) ^ ((urow&7)<<4))) = hq.u;
    __hip_atomic_store((unsigned int*)(houtD + (((size_t)bg*512 + t)*16 + urow)*256 + gc),
                       hq.u, __ATOMIC_RELAXED, SCOPE_AGENT);
    __syncthreads();   // all stores drained (vmcnt0 before barrier)
    if(tid==0)
      __hip_atomic_store(myFlag, (unsigned)(t+1), __ATOMIC_RELEASE, SCOPE_AGENT);
  }
}

// ---------------- attention pooling ----------------
// 128 blocks (one per batch elem), 512 threads. LDS < 36 KB.
__global__ __launch_bounds__(512) void attn_pool(
    const __bf16* __restrict__ h1,   // [2][8][512][16][256] bf16 (bwd in scan order)
    const float*  __restrict__ Wa1,  // [64][512]
    const float*  __restrict__ Wa2,  // [64]
    float* __restrict__ out)         // [128][512]
{
  __shared__ __attribute__((aligned(16))) __bf16 Ws[64*256]; // 32 KB (swizzled)
  __shared__ float scoreL[512];
  __shared__ float red[16];
  const int tid = threadIdx.x, wave = tid>>6, lane = tid&63;
  const int b = blockIdx.x, bg = b>>4, rb = b&15;
  const __bf16* h1F = h1;
  const __bf16* h1B = h1 + (size_t)65536*256;

  float wa2v[4];
#pragma unroll
  for(int ni=0;ni<4;++ni) wa2v[ni] = Wa2[ni*16 + (lane&15)];

  f32x4 acc[4][4];
#pragma unroll
  for(int mi=0;mi<4;++mi)
#pragma unroll
    for(int ni=0;ni<4;++ni) acc[mi][ni] = f32x4{0.f,0.f,0.f,0.f};

  // ---- pass 0: fwd features, Wa1 k in [0,256) ----
  for(int it=0; it<32; ++it){
    int idx = it*512 + tid;
    int n = idx>>8, k = idx&255;
    *(__bf16*)((char*)Ws + n*512 + ((k*2) ^ ((n&7)<<4))) = (__bf16)Wa1[n*512 + k];
  }
  __syncthreads();
#pragma unroll
  for(int mi=0;mi<4;++mi){
    int tA = (wave*4+mi)*16 + (lane&15);
    const __bf16* arow = h1F + (((size_t)bg*512 + tA)*16 + rb)*256;
#pragma unroll
    for(int kb=0;kb<8;++kb){
      int kk = kb*32 + (lane>>4)*8;
      bf16x8 a = *(const bf16x8*)(arow + kk);
#pragma unroll
      for(int ni=0;ni<4;++ni){
        int n = ni*16 + (lane&15);
        bf16x8 w = *(const bf16x8*)((const char*)Ws + n*512 + ((kk*2) ^ ((n&7)<<4)));
        acc[mi][ni] = MFMA16(a, w, acc[mi][ni]);
      }
    }
  }
  __syncthreads();
  // ---- pass 1: bwd features, Wa1 k in [256,512) ----
  for(int it=0; it<32; ++it){
    int idx = it*512 + tid;
    int n = idx>>8, k = idx&255;
    *(__bf16*)((char*)Ws + n*512 + ((k*2) ^ ((n&7)<<4))) = (__bf16)Wa1[n*512 + 256 + k];
  }
  __syncthreads();
#pragma unroll
  for(int mi=0;mi<4;++mi){
    int tA = (wave*4+mi)*16 + (lane&15);
    const __bf16* arow = h1B + (((size_t)bg*512 + (511-tA))*16 + rb)*256;
#pragma unroll
    for(int kb=0;kb<8;++kb){
      int kk = kb*32 + (lane>>4)*8;
      bf16x8 a = *(const bf16x8*)(arow + kk);
#pragma unroll
      for(int ni=0;ni<4;++ni){
        int n = ni*16 + (lane&15);
        bf16x8 w = *(const bf16x8*)((const char*)Ws + n*512 + ((kk*2) ^ ((n&7)<<4)));
        acc[mi][ni] = MFMA16(a, w, acc[mi][ni]);
      }
    }
  }
  // ---- scores ----
#pragma unroll
  for(int mi=0;mi<4;++mi){
    float sp[4] = {0.f,0.f,0.f,0.f};
#pragma unroll
    for(int ni=0;ni<4;++ni)
#pragma unroll
      for(int i=0;i<4;++i) sp[i] += tanh_s(acc[mi][ni][i]) * wa2v[ni];
#pragma unroll
    for(int i=0;i<4;++i){
      float v = sp[i];
      v += __shfl_xor(v, 1, 64); v += __shfl_xor(v, 2, 64);
      v += __shfl_xor(v, 4, 64); v += __shfl_xor(v, 8, 64);
      if((lane&15) == 0) scoreL[(wave*4+mi)*16 + (lane>>4)*4 + i] = v;
    }
  }
  __syncthreads();
  // ---- softmax over t ----
  float sv = scoreL[tid];
  float mx = sv;
  for(int o=32;o>=1;o>>=1) mx = fmaxf(mx, __shfl_xor(mx, o, 64));
  if(lane==0) red[wave] = mx;
  __syncthreads();
  if(tid==0){ float mm=red[0]; for(int i=1;i<8;++i) mm=fmaxf(mm,red[i]); red[8]=mm; }
  __syncthreads();
  mx = red[8];
  float e = __expf(sv - mx);
  float ss = e;
  for(int o=32;o>=1;o>>=1) ss += __shfl_xor(ss, o, 64);
  if(lane==0) red[wave] = ss;
  __syncthreads();
  if(tid==0){ float s2=0.f; for(int i=0;i<8;++i) s2+=red[i]; red[9]=s2; }
  __syncthreads();
  float wgt = e / red[9];
  scoreL[tid] = wgt;
  __syncthreads();
  // ---- weighted sum ----
  const int j = tid;
  const bool bwd = (j >= 256);
  const int jj = bwd ? (j - 256) : j;
  const __bf16* hsrc = bwd ? h1B : h1F;
  float a0=0.f,a1=0.f,a2=0.f,a3=0.f;
  for(int t=0;t<512;t+=4){
#pragma unroll
    for(int u=0;u<4;++u){
      int tt = t + u;
      size_t tr = bwd ? (size_t)(511 - tt) : (size_t)tt;
      float val = (float)hsrc[(((size_t)bg*512 + tr)*16 + rb)*256 + jj];
      float wt = scoreL[tt];
      if(u==0) a0 += wt*val; else if(u==1) a1 += wt*val;
      else if(u==2) a2 += wt*val; else a3 += wt*val;
    }
  }
  out[(size_t)b*512 + j] = (a0+a1)+(a2+a3);
}

// ---------------- launch ----------------
#define H_BYTES 67108864ull   // [2][65536][256] bf16

extern "C" void kernel_launch(void* const* d_in, const int* in_sizes, int n_in,
                              void* d_out, int out_size, void* d_ws, size_t ws_size,
                              hipStream_t stream)
{
  (void)in_sizes; (void)n_in;
  const float* x     = (const float*)d_in[0];
  const float* WihF0 = (const float*)d_in[1];
  const float* WhhF0 = (const float*)d_in[2];
  const float* bihF0 = (const float*)d_in[3];
  const float* bhhF0 = (const float*)d_in[4];
  const float* WihF1 = (const float*)d_in[5];
  const float* WhhF1 = (const float*)d_in[6];
  const float* bihF1 = (const float*)d_in[7];
  const float* bhhF1 = (const float*)d_in[8];
  const float* WihB0 = (const float*)d_in[9];
  const float* WhhB0 = (const float*)d_in[10];
  const float* bihB0 = (const float*)d_in[11];
  const float* bhhB0 = (const float*)d_in[12];
  const float* WihB1 = (const float*)d_in[13];
  const float* WhhB1 = (const float*)d_in[14];
  const float* bihB1 = (const float*)d_in[15];
  const float* bhhB1 = (const float*)d_in[16];
  const float* Wa1   = (const float*)d_in[17];
  const float* Wa2   = (const float*)d_in[18];
  float* out = (float*)d_out;

  if(ws_size < 2*H_BYTES + 16384){
    // diagnostic signature: workspace too small for this design
    fill_sentinel<<<(out_size+255)/256, 256, 0, stream>>>(out, out_size);
    return;
  }

  char* ws = (char*)d_ws;
  __bf16* h0 = (__bf16*)ws;
  __bf16* h1 = (__bf16*)(ws + H_BYTES);
  unsigned int* flags = (unsigned int*)(ws + 2*H_BYTES);

  hipMemsetAsync(flags, 0, 16384, stream);

  lstm_fused<true ><<<64, 512, 0, stream>>>(
      x, (const __bf16*)0,
      WihF0, WihB0, WhhF0, WhhB0, bihF0, bhhF0, bihB0, bhhB0,
      h0, flags);
  lstm_fused<false><<<64, 512, 0, stream>>>(
      (const float*)0, h0,
      WihF1, WihB1, WhhF1, WhhB1, bihF1, bhhF1, bihB1, bhhB1,
      h1, flags + 2048);
  attn_pool<<<128, 512, 0, stream>>>(h1, Wa1, Wa2, out);
}